// Round 13
// baseline (182.357 us; speedup 1.0000x reference)
//
#include <hip/hip_runtime.h>
#include <stdint.h>

#define BB 4
#define TT 2048
#define HH 1024
#define NN 16
#define KK 1024           // GEMM K  (= H)
#define GG 1024           // GEMM out cols (= H)
#define MM (BB*TT)        // GEMM rows
#define NCHUNK 128
#define TC (TT/NCHUNK)    // 16 timesteps per chunk
#define HB 256            // h-columns per scan block (= blockDim)

#if __has_builtin(__builtin_amdgcn_exp2f)
#define FAST_EXP2(x) __builtin_amdgcn_exp2f(x)
#else
#define FAST_EXP2(x) __expf((x) * 0.6931471805599453f)
#endif
#define EXPSCALE 1.4426950408889634f

typedef __attribute__((ext_vector_type(8))) short short8;
typedef __attribute__((ext_vector_type(4))) float f32x4;

__device__ __forceinline__ unsigned short f2bf(float f) {
  union { float f; unsigned u; } a; a.f = f;
  unsigned u = a.u;
  u += 0x7fffu + ((u >> 16) & 1u);   // round-to-nearest-even
  return (unsigned short)(u >> 16);
}

__device__ __forceinline__ float bf2f(unsigned short v) {
  union { unsigned u; float f; } a; a.u = ((unsigned)v) << 16;
  return a.f;
}

// merged converter: [0, n4a) -> x, [n4a, n4a+n4b) -> W
__global__ __launch_bounds__(256) void cvt2_f32_bf16(const float* __restrict__ srcA,
                                                     unsigned short* __restrict__ dstA, int n4a,
                                                     const float* __restrict__ srcB,
                                                     unsigned short* __restrict__ dstB, int n4b) {
  int i = blockIdx.x * blockDim.x + threadIdx.x;
  const float* s; unsigned short* d; int j;
  if (i < n4a) { s = srcA; d = dstA; j = i; }
  else         { s = srcB; d = dstB; j = i - n4a; if (j >= n4b) return; }
  float4 a = ((const float4*)s)[j];
  ushort4 o;
  o.x = f2bf(a.x); o.y = f2bf(a.y); o.z = f2bf(a.z); o.w = f2bf(a.w);
  ((ushort4*)d)[j] = o;
}

// dt[(b,t),g] = softplus( sum_k x[(b,t),k]*W[g,k] + b_dt[g] ), fp16 [M,G].
// 128x64 tile, BK=64: 16 MFMA per barrier-pair, 1024 blocks = 4/CU. (verified r7/r10)
__global__ __launch_bounds__(256, 4) void gemm_dt(const unsigned short* __restrict__ xb,
                                                  const unsigned short* __restrict__ wb,
                                                  const float* __restrict__ b_dt,
                                                  _Float16* __restrict__ dtH) {
  __shared__ short lsA[128 * 64];   // 16 KB
  __shared__ short lsB[64 * 64];    //  8 KB
  const int tid  = threadIdx.x;
  const int w    = tid >> 6;
  const int lane = tid & 63;
  const int bid  = blockIdx.x;
  const int swz  = (bid & 7) * 128 + (bid >> 3);   // 8 XCDs x 128 (bijective)
  const int m0 = (swz >> 4) * 128;                 // 64 m-tiles
  const int g0 = (swz & 15) * 64;                  // 16 g-tiles

  const int r8 = lane >> 3;             // row-within-8
  const int c8 = (lane & 7) * 8;        // col (shorts)
  const unsigned short* gA[4];
  short*                lA[4];
#pragma unroll
  for (int q = 0; q < 4; ++q) {
    const int row = w * 32 + q * 8 + r8;
    gA[q] = xb + (size_t)(m0 + row) * KK + c8;
    lA[q] = lsA + row * 64;
  }
  const unsigned short* gB[2];
  short*                lB[2];
#pragma unroll
  for (int q = 0; q < 2; ++q) {
    const int row = w * 16 + q * 8 + r8;
    gB[q] = wb + (size_t)(g0 + row) * KK + c8;
    lB[q] = lsB + row * 64;
  }

  const int wm   = (w >> 1) * 64;    // wave tile: 64x32
  const int wg   = (w & 1) * 32;
  const int lrow = lane & 15;
  const int lq   = lane >> 4;

  int aoff[4][2], boff[2][2];
#pragma unroll
  for (int mi = 0; mi < 4; ++mi) {
    const int row = wm + mi * 16 + lrow;
    aoff[mi][0] = row * 64 + lq * 8;
    aoff[mi][1] = row * 64 + 32 + lq * 8;
  }
#pragma unroll
  for (int ni = 0; ni < 2; ++ni) {
    const int row = wg + ni * 16 + lrow;
    boff[ni][0] = row * 64 + lq * 8;
    boff[ni][1] = row * 64 + 32 + lq * 8;
  }

  f32x4 acc[4][2];
  const f32x4 zero = {0.f, 0.f, 0.f, 0.f};
#pragma unroll
  for (int i = 0; i < 4; ++i)
#pragma unroll
    for (int j = 0; j < 2; ++j) acc[i][j] = zero;

  for (int kt = 0; kt < KK / 64; ++kt) {
    const int ko = kt * 64;
#pragma unroll
    for (int q = 0; q < 4; ++q)
      __builtin_amdgcn_global_load_lds((__attribute__((address_space(1))) void*)(gA[q] + ko),
                                       (__attribute__((address_space(3))) void*)(lA[q]), 16, 0, 0);
#pragma unroll
    for (int q = 0; q < 2; ++q)
      __builtin_amdgcn_global_load_lds((__attribute__((address_space(1))) void*)(gB[q] + ko),
                                       (__attribute__((address_space(3))) void*)(lB[q]), 16, 0, 0);
    __syncthreads();

#pragma unroll
    for (int kk = 0; kk < 2; ++kk) {
      short8 af[4], bfr[2];
#pragma unroll
      for (int mi = 0; mi < 4; ++mi) af[mi] = *(const short8*)&lsA[aoff[mi][kk]];
#pragma unroll
      for (int ni = 0; ni < 2; ++ni) bfr[ni] = *(const short8*)&lsB[boff[ni][kk]];
#pragma unroll
      for (int mi = 0; mi < 4; ++mi)
#pragma unroll
        for (int ni = 0; ni < 2; ++ni)
          acc[mi][ni] = __builtin_amdgcn_mfma_f32_16x16x32_bf16(af[mi], bfr[ni], acc[mi][ni], 0, 0, 0);
    }
    __syncthreads();
  }

  const int mrow = m0 + wm + lq * 4;
#pragma unroll
  for (int ni = 0; ni < 2; ++ni) {
    const int g = g0 + wg + ni * 16 + lrow;
    const float bias = b_dt[g];
#pragma unroll
    for (int mi = 0; mi < 4; ++mi)
#pragma unroll
      for (int r = 0; r < 4; ++r) {
        float z = acc[mi][ni][r] + bias;
        dtH[(size_t)(mrow + mi * 16 + r) * GG + g] =
            (_Float16)(fmaxf(z, 0.f) + __logf(1.f + __expf(-fabsf(z))));
      }
  }
}

// ---- chunk-parallel scan, thread = h, 16 n-states in registers ------------
// NCHUNK=128, (256,4) [VGPR=64 naturally -> HW runs 8 blocks/CU], bf16 u,
// fp16 chunk states in [c][b][n][h] layout (coalesced wave stores).
__global__ __launch_bounds__(256, 4) void ssm_phase1(const unsigned short* __restrict__ xb,
                                                     const _Float16* __restrict__ dtH,
                                                     const float* __restrict__ A_log,
                                                     _Float16* __restrict__ slocH,
                                                     float* __restrict__ sdArr) {
  const int tid = threadIdx.x;
  const int bid = blockIdx.x;
  const int hb = bid & (HH / HB - 1);
  const int b  = (bid >> 2) & (BB - 1);
  const int c  = bid >> 4;                // 0..127
  const int h  = hb * HB + tid;

  const size_t base = ((size_t)b * TT + c * TC) * HH + h;
  const unsigned short* up = xb + base;
  const _Float16*       dp = dtH + base;

  float Ae[NN];
#pragma unroll
  for (int n = 0; n < NN; n += 4) {
    f32x4 av = *(const f32x4*)&A_log[h * NN + n];
#pragma unroll
    for (int q = 0; q < 4; ++q) Ae[n + q] = -__expf(av[q]) * EXPSCALE;
  }

  float s[NN];
#pragma unroll
  for (int n = 0; n < NN; ++n) s[n] = 0.f;
  float sd = 0.f;

#pragma unroll
  for (int j = 0; j < TC / 8; ++j) {
    unsigned short uu[8]; _Float16 dv[8];
#pragma unroll
    for (int i = 0; i < 8; ++i) {
      uu[i] = up[(size_t)(j * 8 + i) * HH];
      dv[i] = dp[(size_t)(j * 8 + i) * HH];
    }
#pragma unroll
    for (int i = 0; i < 8; ++i) {
      const float dtv = (float)dv[i];
      const float du  = dtv * bf2f(uu[i]);
      sd += dtv;
#pragma unroll
      for (int n = 0; n < NN; ++n) {
        const float ab = FAST_EXP2(dtv * Ae[n]);
        s[n] = fmaf(ab, s[n], du);
      }
    }
  }

  // [c][b][n][h]: 16 coalesced wave-stores (fp16 halves the write traffic)
  _Float16* sp = slocH + ((size_t)(c * BB + b) * NN) * HH + h;
#pragma unroll
  for (int n = 0; n < NN; ++n) sp[(size_t)n * HH] = (_Float16)s[n];
  sdArr[(size_t)(c * BB + b) * HH + h] = sd;
}

// phase 2: sequential combine over chunks (s' units); slocH becomes carry-in.
// id decodes the [b][n][h] inner layout.
__global__ __launch_bounds__(256) void ssm_phase2(_Float16* __restrict__ slocH,
                                                  const float* __restrict__ sdArr,
                                                  const float* __restrict__ A_log,
                                                  const float* __restrict__ Bm_,
                                                  float* __restrict__ stateOut) {
  const int id = blockIdx.x * 256 + threadIdx.x;   // 65536 = b*16384 + n*1024 + h
  const int h  = id & (HH - 1);
  const int n  = (id >> 10) & (NN - 1);
  const int b  = id >> 14;
  const int hn = h * NN + n;
  const int bh = b * HH + h;
  const float Ae = -__expf(A_log[hn]) * EXPSCALE;
  float carry = 0.f;
#pragma unroll 8
  for (int ch = 0; ch < NCHUNK; ++ch) {
    const size_t idx = (size_t)ch * (BB * HH * NN) + id;
    const float sl = (float)slocH[idx];
    const float dc = FAST_EXP2(Ae * sdArr[(size_t)ch * (BB * HH) + bh]);
    slocH[idx] = (_Float16)carry;
    carry = fmaf(dc, carry, sl);
  }
  stateOut[(size_t)bh * NN + n] = Bm_[hn] * carry;   // [b][h][n] output layout
}

// phase 3: rescan each chunk from its fp16 carry-in, emitting y.
__global__ __launch_bounds__(256, 4) void ssm_phase3(const unsigned short* __restrict__ xb,
                                                     const _Float16* __restrict__ dtH,
                                                     const float* __restrict__ A_log,
                                                     const float* __restrict__ Bm_,
                                                     const float* __restrict__ Cm_,
                                                     const float* __restrict__ Dv_,
                                                     const _Float16* __restrict__ carryH,
                                                     float* __restrict__ out) {
  const int tid = threadIdx.x;
  const int bid = blockIdx.x;
  const int hb = bid & (HH / HB - 1);
  const int b  = (bid >> 2) & (BB - 1);
  const int c  = bid >> 4;
  const int h  = hb * HB + tid;

  const size_t base = ((size_t)b * TT + c * TC) * HH + h;
  const unsigned short* up = xb + base;
  const _Float16*       dp = dtH + base;
  float*                yo = out + base;

  float Ae[NN], Cb[NN];
#pragma unroll
  for (int n = 0; n < NN; n += 4) {
    f32x4 av = *(const f32x4*)&A_log[h * NN + n];
    f32x4 cv = *(const f32x4*)&Cm_[h * NN + n];
    f32x4 bv = *(const f32x4*)&Bm_[h * NN + n];
#pragma unroll
    for (int q = 0; q < 4; ++q) {
      Ae[n + q] = -__expf(av[q]) * EXPSCALE;
      Cb[n + q] = cv[q] * bv[q];                 // C*B folded (s' units)
    }
  }
  const float Dv = Dv_[h];

  float s[NN];
  const _Float16* cp = carryH + ((size_t)(c * BB + b) * NN) * HH + h;
#pragma unroll
  for (int n = 0; n < NN; ++n) s[n] = (float)cp[(size_t)n * HH];   // coalesced

#pragma unroll
  for (int j = 0; j < TC / 8; ++j) {
    unsigned short uu[8]; _Float16 dv[8];
#pragma unroll
    for (int i = 0; i < 8; ++i) {
      uu[i] = up[(size_t)(j * 8 + i) * HH];
      dv[i] = dp[(size_t)(j * 8 + i) * HH];
    }
#pragma unroll
    for (int i = 0; i < 8; ++i) {
      const float dtv = (float)dv[i];
      const float uv  = bf2f(uu[i]);
      const float du  = dtv * uv;
      float y0 = Dv * uv, y1 = 0.f, y2 = 0.f, y3 = 0.f;
#pragma unroll
      for (int n = 0; n < NN; n += 4) {
        float ab;
        ab = FAST_EXP2(dtv * Ae[n]);     s[n]     = fmaf(ab, s[n],     du); y0 = fmaf(Cb[n],     s[n],     y0);
        ab = FAST_EXP2(dtv * Ae[n + 1]); s[n + 1] = fmaf(ab, s[n + 1], du); y1 = fmaf(Cb[n + 1], s[n + 1], y1);
        ab = FAST_EXP2(dtv * Ae[n + 2]); s[n + 2] = fmaf(ab, s[n + 2], du); y2 = fmaf(Cb[n + 2], s[n + 2], y2);
        ab = FAST_EXP2(dtv * Ae[n + 3]); s[n + 3] = fmaf(ab, s[n + 3], du); y3 = fmaf(Cb[n + 3], s[n + 3], y3);
      }
      yo[(size_t)(j * 8 + i) * HH] = (y0 + y1) + (y2 + y3);
    }
  }
}

extern "C" void kernel_launch(void* const* d_in, const int* in_sizes, int n_in,
                              void* d_out, int out_size, void* d_ws, size_t ws_size,
                              hipStream_t stream) {
  const float* x     = (const float*)d_in[0];
  const float* A_log = (const float*)d_in[1];
  const float* B_mat = (const float*)d_in[2];
  const float* C_mat = (const float*)d_in[3];
  const float* D_vec = (const float*)d_in[4];
  const float* W_dt  = (const float*)d_in[5];
  const float* b_dt  = (const float*)d_in[6];
  float* out = (float*)d_out;

  char* ws = (char*)d_ws;
  unsigned short* xb    = (unsigned short*)(ws);             // [0,16M)  bf16 x (live thru p3)
  unsigned short* wb    = (unsigned short*)(ws + 16777216);  // [16M,18M) bf16 W
  _Float16*       dtH   = (_Float16*)(ws + 18874368);        // [18M,34M) fp16 dt
  _Float16*       slocH = (_Float16*)(ws + 35651584);        // [34M,50M) fp16 chunk states
  float*          sdArr = (float*)(ws + 52428800);           // [50M,52M) sum-dt
  float* stateOut = out + (size_t)BB * TT * HH;

  const int n4x = MM * KK / 4, n4w = GG * KK / 4;
  cvt2_f32_bf16<<<(n4x + n4w + 255) / 256, 256, 0, stream>>>(x, xb, n4x, W_dt, wb, n4w);
  gemm_dt<<<(MM / 128) * (GG / 64), 256, 0, stream>>>(xb, wb, b_dt, dtH);

  const int nblk = (HH / HB) * BB * NCHUNK;   // 2048 (HW fits 8 blocks/CU at VGPR=64)
  ssm_phase1<<<nblk, 256, 0, stream>>>(xb, dtH, A_log, slocH, sdArr);
  ssm_phase2<<<(BB * HH * NN) / 256, 256, 0, stream>>>(slocH, sdArr, A_log, B_mat, stateOut);
  ssm_phase3<<<nblk, 256, 0, stream>>>(xb, dtH, A_log, B_mat, C_mat, D_vec, slocH, out);
}

// Round 14
// 173.269 us; speedup vs baseline: 1.0525x; 1.0525x over previous
//
#include <hip/hip_runtime.h>
#include <stdint.h>

#define BB 4
#define TT 2048
#define HH 1024
#define NN 16
#define KK 1024           // GEMM K  (= H)
#define GG 1024           // GEMM out cols (= H)
#define MM (BB*TT)        // GEMM rows
#define NCHUNK 64
#define TC (TT/NCHUNK)    // 32 timesteps per chunk
#define HB 256            // h-columns per scan block (= blockDim)

#if __has_builtin(__builtin_amdgcn_exp2f)
#define FAST_EXP2(x) __builtin_amdgcn_exp2f(x)
#else
#define FAST_EXP2(x) __expf((x) * 0.6931471805599453f)
#endif
#define EXPSCALE 1.4426950408889634f

typedef __attribute__((ext_vector_type(8))) short short8;
typedef __attribute__((ext_vector_type(4))) float f32x4;

__device__ __forceinline__ unsigned short f2bf(float f) {
  union { float f; unsigned u; } a; a.f = f;
  unsigned u = a.u;
  u += 0x7fffu + ((u >> 16) & 1u);   // round-to-nearest-even
  return (unsigned short)(u >> 16);
}

__device__ __forceinline__ float bf2f(unsigned short v) {
  union { unsigned u; float f; } a; a.u = ((unsigned)v) << 16;
  return a.f;
}

// merged converter: [0, n4a) -> x, [n4a, n4a+n4b) -> W
__global__ __launch_bounds__(256) void cvt2_f32_bf16(const float* __restrict__ srcA,
                                                     unsigned short* __restrict__ dstA, int n4a,
                                                     const float* __restrict__ srcB,
                                                     unsigned short* __restrict__ dstB, int n4b) {
  int i = blockIdx.x * blockDim.x + threadIdx.x;
  const float* s; unsigned short* d; int j;
  if (i < n4a) { s = srcA; d = dstA; j = i; }
  else         { s = srcB; d = dstB; j = i - n4a; if (j >= n4b) return; }
  float4 a = ((const float4*)s)[j];
  ushort4 o;
  o.x = f2bf(a.x); o.y = f2bf(a.y); o.z = f2bf(a.z); o.w = f2bf(a.w);
  ((ushort4*)d)[j] = o;
}

// dt[(b,t),g] = softplus( sum_k x[(b,t),k]*W[g,k] + b_dt[g] ), fp16 [M,G].
// 128x64 tile, BK=64 (r12-verified) + T2 LDS XOR-swizzle:
//   - staging uses pre-swizzled GLOBAL source col ((lane&7)^r8)*8 (rule #21),
//   - ds_read offsets apply the same XOR -> 16-way bank conflict becomes 2-way.
__global__ __launch_bounds__(256, 4) void gemm_dt(const unsigned short* __restrict__ xb,
                                                  const unsigned short* __restrict__ wb,
                                                  const float* __restrict__ b_dt,
                                                  _Float16* __restrict__ dtH) {
  __shared__ short lsA[128 * 64];   // 16 KB
  __shared__ short lsB[64 * 64];    //  8 KB
  const int tid  = threadIdx.x;
  const int w    = tid >> 6;
  const int lane = tid & 63;
  const int bid  = blockIdx.x;
  const int swz  = (bid & 7) * 128 + (bid >> 3);   // 8 XCDs x 128 (bijective)
  const int m0 = (swz >> 4) * 128;                 // 64 m-tiles
  const int g0 = (swz & 15) * 64;                  // 16 g-tiles

  const int r8  = lane >> 3;                  // row-within-8
  const int c8x = ((lane & 7) ^ r8) * 8;      // pre-swizzled source col (shorts)
  const unsigned short* gA[4];
  short*                lA[4];
#pragma unroll
  for (int q = 0; q < 4; ++q) {
    const int row = w * 32 + q * 8 + r8;
    gA[q] = xb + (size_t)(m0 + row) * KK + c8x;
    lA[q] = lsA + row * 64;                   // linear LDS dest (wave-uniform+lane*16B)
  }
  const unsigned short* gB[2];
  short*                lB[2];
#pragma unroll
  for (int q = 0; q < 2; ++q) {
    const int row = w * 16 + q * 8 + r8;
    gB[q] = wb + (size_t)(g0 + row) * KK + c8x;
    lB[q] = lsB + row * 64;
  }

  const int wm   = (w >> 1) * 64;    // wave tile: 64x32
  const int wg   = (w & 1) * 32;
  const int lrow = lane & 15;
  const int lq   = lane >> 4;

  // swizzled LDS read offsets (shorts): row*64 + (((kk*4+lq)^(row&7))<<3)
  int aoff[4][2], boff[2][2];
#pragma unroll
  for (int mi = 0; mi < 4; ++mi) {
    const int row = wm + mi * 16 + lrow;
#pragma unroll
    for (int kk = 0; kk < 2; ++kk)
      aoff[mi][kk] = row * 64 + (((kk * 4 + lq) ^ (row & 7)) << 3);
  }
#pragma unroll
  for (int ni = 0; ni < 2; ++ni) {
    const int row = wg + ni * 16 + lrow;
#pragma unroll
    for (int kk = 0; kk < 2; ++kk)
      boff[ni][kk] = row * 64 + (((kk * 4 + lq) ^ (row & 7)) << 3);
  }

  f32x4 acc[4][2];
  const f32x4 zero = {0.f, 0.f, 0.f, 0.f};
#pragma unroll
  for (int i = 0; i < 4; ++i)
#pragma unroll
    for (int j = 0; j < 2; ++j) acc[i][j] = zero;

  for (int kt = 0; kt < KK / 64; ++kt) {
    const int ko = kt * 64;
#pragma unroll
    for (int q = 0; q < 4; ++q)
      __builtin_amdgcn_global_load_lds((__attribute__((address_space(1))) void*)(gA[q] + ko),
                                       (__attribute__((address_space(3))) void*)(lA[q]), 16, 0, 0);
#pragma unroll
    for (int q = 0; q < 2; ++q)
      __builtin_amdgcn_global_load_lds((__attribute__((address_space(1))) void*)(gB[q] + ko),
                                       (__attribute__((address_space(3))) void*)(lB[q]), 16, 0, 0);
    __syncthreads();

#pragma unroll
    for (int kk = 0; kk < 2; ++kk) {
      short8 af[4], bfr[2];
#pragma unroll
      for (int mi = 0; mi < 4; ++mi) af[mi] = *(const short8*)&lsA[aoff[mi][kk]];
#pragma unroll
      for (int ni = 0; ni < 2; ++ni) bfr[ni] = *(const short8*)&lsB[boff[ni][kk]];
#pragma unroll
      for (int mi = 0; mi < 4; ++mi)
#pragma unroll
        for (int ni = 0; ni < 2; ++ni)
          acc[mi][ni] = __builtin_amdgcn_mfma_f32_16x16x32_bf16(af[mi], bfr[ni], acc[mi][ni], 0, 0, 0);
    }
    __syncthreads();
  }

  const int mrow = m0 + wm + lq * 4;
#pragma unroll
  for (int ni = 0; ni < 2; ++ni) {
    const int g = g0 + wg + ni * 16 + lrow;
    const float bias = b_dt[g];
#pragma unroll
    for (int mi = 0; mi < 4; ++mi)
#pragma unroll
      for (int r = 0; r < 4; ++r) {
        float z = acc[mi][ni][r] + bias;
        dtH[(size_t)(mrow + mi * 16 + r) * GG + g] =
            (_Float16)(fmaxf(z, 0.f) + __logf(1.f + __expf(-fabsf(z))));
      }
  }
}

// ---- chunk-parallel scan, thread = h, 16 n-states in registers ------------
// r12-verified: (256,4), 1024 blocks, bf16 u, sloc [c][b][n][h] coalesced.
__global__ __launch_bounds__(256, 4) void ssm_phase1(const unsigned short* __restrict__ xb,
                                                     const _Float16* __restrict__ dtH,
                                                     const float* __restrict__ A_log,
                                                     float* __restrict__ sloc,
                                                     float* __restrict__ sdArr) {
  const int tid = threadIdx.x;
  const int bid = blockIdx.x;
  const int hb = bid & (HH / HB - 1);
  const int b  = (bid >> 2) & (BB - 1);
  const int c  = bid >> 4;
  const int h  = hb * HB + tid;

  const size_t base = ((size_t)b * TT + c * TC) * HH + h;
  const unsigned short* up = xb + base;
  const _Float16*       dp = dtH + base;

  float Ae[NN];
#pragma unroll
  for (int n = 0; n < NN; n += 4) {
    f32x4 av = *(const f32x4*)&A_log[h * NN + n];
#pragma unroll
    for (int q = 0; q < 4; ++q) Ae[n + q] = -__expf(av[q]) * EXPSCALE;
  }

  float s[NN];
#pragma unroll
  for (int n = 0; n < NN; ++n) s[n] = 0.f;
  float sd = 0.f;

#pragma unroll
  for (int j = 0; j < TC / 8; ++j) {
    unsigned short uu[8]; _Float16 dv[8];
#pragma unroll
    for (int i = 0; i < 8; ++i) {
      uu[i] = up[(size_t)(j * 8 + i) * HH];
      dv[i] = dp[(size_t)(j * 8 + i) * HH];
    }
#pragma unroll
    for (int i = 0; i < 8; ++i) {
      const float dtv = (float)dv[i];
      const float du  = dtv * bf2f(uu[i]);
      sd += dtv;
#pragma unroll
      for (int n = 0; n < NN; ++n) {
        const float ab = FAST_EXP2(dtv * Ae[n]);
        s[n] = fmaf(ab, s[n], du);
      }
    }
  }

  // [c][b][n][h]: 16 coalesced 256B wave-stores
  float* sp = sloc + ((size_t)(c * BB + b) * NN) * HH + h;
#pragma unroll
  for (int n = 0; n < NN; ++n) sp[(size_t)n * HH] = s[n];
  sdArr[(size_t)(c * BB + b) * HH + h] = sd;
}

// phase 2: sequential combine over chunks (s' units); sloc becomes carry-in.
__global__ __launch_bounds__(256) void ssm_phase2(float* __restrict__ sloc,
                                                  const float* __restrict__ sdArr,
                                                  const float* __restrict__ A_log,
                                                  const float* __restrict__ Bm_,
                                                  float* __restrict__ stateOut) {
  const int id = blockIdx.x * 256 + threadIdx.x;   // 65536 = b*16384 + n*1024 + h
  const int h  = id & (HH - 1);
  const int n  = (id >> 10) & (NN - 1);
  const int b  = id >> 14;
  const int hn = h * NN + n;
  const int bh = b * HH + h;
  const float Ae = -__expf(A_log[hn]) * EXPSCALE;
  float carry = 0.f;
#pragma unroll 8
  for (int ch = 0; ch < NCHUNK; ++ch) {
    const size_t idx = (size_t)ch * (BB * HH * NN) + id;
    const float sl = sloc[idx];
    const float dc = FAST_EXP2(Ae * sdArr[(size_t)ch * (BB * HH) + bh]);
    sloc[idx] = carry;
    carry = fmaf(dc, carry, sl);
  }
  stateOut[(size_t)bh * NN + n] = Bm_[hn] * carry;   // [b][h][n] output layout
}

// phase 3: rescan each chunk from its carry-in, emitting y (4-way partial dot).
__global__ __launch_bounds__(256, 4) void ssm_phase3(const unsigned short* __restrict__ xb,
                                                     const _Float16* __restrict__ dtH,
                                                     const float* __restrict__ A_log,
                                                     const float* __restrict__ Bm_,
                                                     const float* __restrict__ Cm_,
                                                     const float* __restrict__ Dv_,
                                                     const float* __restrict__ carryBuf,
                                                     float* __restrict__ out) {
  const int tid = threadIdx.x;
  const int bid = blockIdx.x;
  const int hb = bid & (HH / HB - 1);
  const int b  = (bid >> 2) & (BB - 1);
  const int c  = bid >> 4;
  const int h  = hb * HB + tid;

  const size_t base = ((size_t)b * TT + c * TC) * HH + h;
  const unsigned short* up = xb + base;
  const _Float16*       dp = dtH + base;
  float*                yo = out + base;

  float Ae[NN], Cb[NN];
#pragma unroll
  for (int n = 0; n < NN; n += 4) {
    f32x4 av = *(const f32x4*)&A_log[h * NN + n];
    f32x4 cv = *(const f32x4*)&Cm_[h * NN + n];
    f32x4 bv = *(const f32x4*)&Bm_[h * NN + n];
#pragma unroll
    for (int q = 0; q < 4; ++q) {
      Ae[n + q] = -__expf(av[q]) * EXPSCALE;
      Cb[n + q] = cv[q] * bv[q];                 // C*B folded (s' units)
    }
  }
  const float Dv = Dv_[h];

  float s[NN];
  const float* cp = carryBuf + ((size_t)(c * BB + b) * NN) * HH + h;
#pragma unroll
  for (int n = 0; n < NN; ++n) s[n] = cp[(size_t)n * HH];   // coalesced 256B loads

#pragma unroll
  for (int j = 0; j < TC / 8; ++j) {
    unsigned short uu[8]; _Float16 dv[8];
#pragma unroll
    for (int i = 0; i < 8; ++i) {
      uu[i] = up[(size_t)(j * 8 + i) * HH];
      dv[i] = dp[(size_t)(j * 8 + i) * HH];
    }
#pragma unroll
    for (int i = 0; i < 8; ++i) {
      const float dtv = (float)dv[i];
      const float uv  = bf2f(uu[i]);
      const float du  = dtv * uv;
      float y0 = Dv * uv, y1 = 0.f, y2 = 0.f, y3 = 0.f;
#pragma unroll
      for (int n = 0; n < NN; n += 4) {
        float ab;
        ab = FAST_EXP2(dtv * Ae[n]);     s[n]     = fmaf(ab, s[n],     du); y0 = fmaf(Cb[n],     s[n],     y0);
        ab = FAST_EXP2(dtv * Ae[n + 1]); s[n + 1] = fmaf(ab, s[n + 1], du); y1 = fmaf(Cb[n + 1], s[n + 1], y1);
        ab = FAST_EXP2(dtv * Ae[n + 2]); s[n + 2] = fmaf(ab, s[n + 2], du); y2 = fmaf(Cb[n + 2], s[n + 2], y2);
        ab = FAST_EXP2(dtv * Ae[n + 3]); s[n + 3] = fmaf(ab, s[n + 3], du); y3 = fmaf(Cb[n + 3], s[n + 3], y3);
      }
      yo[(size_t)(j * 8 + i) * HH] = (y0 + y1) + (y2 + y3);
    }
  }
}

extern "C" void kernel_launch(void* const* d_in, const int* in_sizes, int n_in,
                              void* d_out, int out_size, void* d_ws, size_t ws_size,
                              hipStream_t stream) {
  const float* x     = (const float*)d_in[0];
  const float* A_log = (const float*)d_in[1];
  const float* B_mat = (const float*)d_in[2];
  const float* C_mat = (const float*)d_in[3];
  const float* D_vec = (const float*)d_in[4];
  const float* W_dt  = (const float*)d_in[5];
  const float* b_dt  = (const float*)d_in[6];
  float* out = (float*)d_out;

  char* ws = (char*)d_ws;
  unsigned short* xb    = (unsigned short*)(ws);             // [0,16M)  bf16 x (live thru p3)
  unsigned short* wb    = (unsigned short*)(ws + 16777216);  // [16M,18M) bf16 W
  _Float16*       dtH   = (_Float16*)(ws + 18874368);        // [18M,34M) fp16 dt
  float*          sloc  = (float*)(ws + 35651584);           // [34M,50M) chunk states
  float*          sdArr = (float*)(ws + 52428800);           // [50M,51M) sum-dt
  float* stateOut = out + (size_t)BB * TT * HH;

  const int n4x = MM * KK / 4, n4w = GG * KK / 4;
  cvt2_f32_bf16<<<(n4x + n4w + 255) / 256, 256, 0, stream>>>(x, xb, n4x, W_dt, wb, n4w);
  gemm_dt<<<(MM / 128) * (GG / 64), 256, 0, stream>>>(xb, wb, b_dt, dtH);

  const int nblk = (HH / HB) * BB * NCHUNK;   // 1024
  ssm_phase1<<<nblk, 256, 0, stream>>>(xb, dtH, A_log, sloc, sdArr);
  ssm_phase2<<<(BB * HH * NN) / 256, 256, 0, stream>>>(sloc, sdArr, A_log, B_mat, stateOut);
  ssm_phase3<<<nblk, 256, 0, stream>>>(xb, dtH, A_log, B_mat, C_mat, D_vec, sloc, out);
}